// Round 9
// baseline (498.767 us; speedup 1.0000x reference)
//
#include <hip/hip_runtime.h>
#include <stdint.h>

typedef __attribute__((ext_vector_type(8))) short bf16x8;
typedef __attribute__((ext_vector_type(4))) float f32x4;

static __device__ __forceinline__ unsigned short f2b(float f) {
    unsigned int u = __float_as_uint(f);
    unsigned int r = u + 0x7fffu + ((u >> 16) & 1u);   // RNE
    return (unsigned short)(r >> 16);
}
static __device__ __forceinline__ float b2f(unsigned short u) {
    return __uint_as_float((unsigned int)u << 16);
}
static __device__ __forceinline__ f32x4 b2f4(ushort4 u) {
    f32x4 r;
    r[0] = b2f(u.x); r[1] = b2f(u.y); r[2] = b2f(u.z); r[3] = b2f(u.w);
    return r;
}

// ---------------- fused: count_deg (blocks [0,ecnt)) + gemm1 fp32->bf16 (rest) ----------------

__global__ __launch_bounds__(256) void count_and_gemm1(
        const int* __restrict__ dst, int E, int* __restrict__ counts, int ecnt,
        const float* __restrict__ x, const float* __restrict__ W1,
        unsigned short* __restrict__ outb, int N) {
    __shared__ __align__(16) unsigned short hl[64][136];
    int tid = threadIdx.x;
    if ((int)blockIdx.x < ecnt) {
        int e = blockIdx.x * 256 + tid;
        if (e < E) atomicAdd(&counts[dst[e]], 1);
        return;
    }
    int tilebase = (blockIdx.x - ecnt) * 64;
    int wid = tid >> 6, lane = tid & 63;
    int lg = lane >> 4, l15 = lane & 15;

    bf16x8 a[2][4];
    #pragma unroll
    for (int mt = 0; mt < 2; ++mt) {
        int col = wid * 32 + mt * 16 + l15;
        #pragma unroll
        for (int kk = 0; kk < 4; ++kk) {
            bf16x8 af;
            #pragma unroll
            for (int ee = 0; ee < 8; ++ee)
                af[ee] = (short)f2b(W1[(size_t)(kk * 32 + lg * 8 + ee) * 128 + col]);
            a[mt][kk] = af;
        }
    }
    #pragma unroll
    for (int p = 0; p < 4; ++p) {
        int idx = p * 256 + tid;
        int r = idx >> 4, ci = idx & 15;
        int row = tilebase + r;
        if (row >= N) row = N - 1;
        const float* ip = x + (size_t)row * 128 + ci * 8;
        f32x4 x0 = *(const f32x4*)ip;
        f32x4 x1 = *(const f32x4*)(ip + 4);
        uint4 v;
        v.x = (unsigned int)f2b(x0[0]) | ((unsigned int)f2b(x0[1]) << 16);
        v.y = (unsigned int)f2b(x0[2]) | ((unsigned int)f2b(x0[3]) << 16);
        v.z = (unsigned int)f2b(x1[0]) | ((unsigned int)f2b(x1[1]) << 16);
        v.w = (unsigned int)f2b(x1[2]) | ((unsigned int)f2b(x1[3]) << 16);
        *(uint4*)&hl[r][ci * 8] = v;
    }
    __syncthreads();

    f32x4 acc[2][4];
    #pragma unroll
    for (int mt = 0; mt < 2; ++mt)
        #pragma unroll
        for (int nt = 0; nt < 4; ++nt) acc[mt][nt] = (f32x4){0.f, 0.f, 0.f, 0.f};
    #pragma unroll
    for (int kk = 0; kk < 4; ++kk) {
        #pragma unroll
        for (int nt = 0; nt < 4; ++nt) {
            bf16x8 b = *(const bf16x8*)&hl[nt * 16 + l15][kk * 32 + lg * 8];
            acc[0][nt] = __builtin_amdgcn_mfma_f32_16x16x32_bf16(a[0][kk], b, acc[0][nt], 0, 0, 0);
            acc[1][nt] = __builtin_amdgcn_mfma_f32_16x16x32_bf16(a[1][kk], b, acc[1][nt], 0, 0, 0);
        }
    }
    #pragma unroll
    for (int mt = 0; mt < 2; ++mt) {
        int j = wid * 32 + mt * 16 + lg * 4;
        #pragma unroll
        for (int nt = 0; nt < 4; ++nt) {
            int node = tilebase + nt * 16 + l15;
            if (node < N) {
                unsigned int u0 = (unsigned int)f2b(acc[mt][nt][0]) | ((unsigned int)f2b(acc[mt][nt][1]) << 16);
                unsigned int u1 = (unsigned int)f2b(acc[mt][nt][2]) | ((unsigned int)f2b(acc[mt][nt][3]) << 16);
                *(uint2*)(outb + (size_t)node * 128 + j) = make_uint2(u0, u1);
            }
        }
    }
}

// ---------------- CSR build ----------------

__global__ void scan_s1(const int* __restrict__ counts, int N,
                        int* __restrict__ rowstart, float* __restrict__ dinv,
                        int* __restrict__ psum) {
    __shared__ int wsum[16];
    int tid = threadIdx.x, wave = tid >> 6, lane = tid & 63;
    int i = blockIdx.x * 1024 + tid;
    int c = (i < N) ? counts[i] : 0;
    int x = c;
    #pragma unroll
    for (int off = 1; off < 64; off <<= 1) {
        int v = __shfl_up(x, off);
        if (lane >= off) x += v;
    }
    if (lane == 63) wsum[wave] = x;
    __syncthreads();
    int pre = 0, tot = 0;
    #pragma unroll
    for (int w = 0; w < 16; ++w) {
        int s = wsum[w];
        tot += s;
        if (w < wave) pre += s;
    }
    if (i < N) {
        rowstart[i] = pre + x - c;
        dinv[i] = rsqrtf((float)c + 1.0f);
    }
    if (tid == 0) psum[blockIdx.x] = tot;
}

// merged s2+s3: each block locally re-scans psum (nchunk <= 64)
__global__ void scan_s23(const int* __restrict__ psum, int nchunk,
                         int* __restrict__ rowstart, int N, int* __restrict__ cursor) {
    int b = blockIdx.x;
    int pre = 0, tot = 0;
    for (int w = 0; w < nchunk; ++w) {
        int s = psum[w];
        tot += s;
        if (w < b) pre += s;
    }
    int i = b * 1024 + threadIdx.x;
    if (i < N) {
        int r = rowstart[i] + pre;
        rowstart[i] = r;
        cursor[i] = r;
    }
    if (b == 0 && threadIdx.x == 0) rowstart[N] = tot;
}

// packs (src, norm=dinv[src]*dinv[dst]) per CSR slot (arbitrary order within bucket)
__global__ void fill_csr(const int* __restrict__ src, const int* __restrict__ dst, int E,
                         int* __restrict__ cursor, const float* __restrict__ dinv,
                         int2* __restrict__ csr_sn, int* __restrict__ csr_dst,
                         int* __restrict__ csr_eid) {
    int e = blockIdx.x * 256 + threadIdx.x;
    if (e < E) {
        int d = dst[e], s = src[e];
        int p = atomicAdd(&cursor[d], 1);
        float nrm = dinv[s] * dinv[d];
        csr_sn[p] = make_int2(s, __float_as_int(nrm));
        csr_dst[p] = d;
        csr_eid[p] = e;
    }
}

// deterministic re-order: slot -> rowstart[d] + rank(eid within bucket).
// eids are unique -> bijection; output order is bit-identical every call,
// making all downstream fp32 sums deterministic across graph replays.
__global__ void rank_csr(const int* __restrict__ rowstart, const int* __restrict__ csr_dst,
                         const int2* __restrict__ csr_sn, const int* __restrict__ csr_eid,
                         int2* __restrict__ csr_sn2, int* __restrict__ csr_eid2, int E) {
    int p = blockIdx.x * 256 + threadIdx.x;
    if (p >= E) return;
    int d = csr_dst[p];
    int rs = rowstart[d], re = rowstart[d + 1];
    int my = csr_eid[p];
    int rank = 0;
    for (int q = rs; q < re; ++q) rank += (csr_eid[q] < my);
    csr_sn2[rs + rank] = csr_sn[p];
    csr_eid2[rs + rank] = my;
}

// ---------------- fused aggregate(64 nodes -> LDS, bf16) + GEMM ----------------

template <int RELU, int UV>
__global__ __launch_bounds__(256) void agg_gemm(
        const unsigned short* __restrict__ tb, const int* __restrict__ rowstart,
        const int2* __restrict__ csr_sn, const float* __restrict__ dinv,
        const float* __restrict__ bias, const float* __restrict__ W,
        unsigned short* __restrict__ outb, int N) {
    __shared__ __align__(16) unsigned short hl[64][136];
    constexpr int MT = UV ? 4 : 2;
    int tid = threadIdx.x;
    int tilebase = blockIdx.x * 64;

    // ---- aggregate 64 nodes, 8 per pass, 32 lanes/node ----
    int nloc = tid >> 5;          // 0..7
    int c = (tid & 31) * 4;
    #pragma unroll 1
    for (int p = 0; p < 8; ++p) {
        int node = tilebase + p * 8 + nloc;
        if (node >= N) node = N - 1;
        float di = dinv[node];
        f32x4 self = b2f4(*(const ushort4*)(tb + (size_t)node * 128 + c));
        f32x4 acc = *(const f32x4*)(bias + c) + (di * di) * self;
        int e = rowstart[node], re = rowstart[node + 1];
        for (; e + 7 < re; e += 8) {
            int2 p0 = csr_sn[e + 0], p1 = csr_sn[e + 1], p2 = csr_sn[e + 2], p3 = csr_sn[e + 3];
            int2 p4 = csr_sn[e + 4], p5 = csr_sn[e + 5], p6 = csr_sn[e + 6], p7 = csr_sn[e + 7];
            ushort4 r0 = *(const ushort4*)(tb + (size_t)p0.x * 128 + c);
            ushort4 r1 = *(const ushort4*)(tb + (size_t)p1.x * 128 + c);
            ushort4 r2 = *(const ushort4*)(tb + (size_t)p2.x * 128 + c);
            ushort4 r3 = *(const ushort4*)(tb + (size_t)p3.x * 128 + c);
            ushort4 r4 = *(const ushort4*)(tb + (size_t)p4.x * 128 + c);
            ushort4 r5 = *(const ushort4*)(tb + (size_t)p5.x * 128 + c);
            ushort4 r6 = *(const ushort4*)(tb + (size_t)p6.x * 128 + c);
            ushort4 r7 = *(const ushort4*)(tb + (size_t)p7.x * 128 + c);
            acc += __int_as_float(p0.y) * b2f4(r0);
            acc += __int_as_float(p1.y) * b2f4(r1);
            acc += __int_as_float(p2.y) * b2f4(r2);
            acc += __int_as_float(p3.y) * b2f4(r3);
            acc += __int_as_float(p4.y) * b2f4(r4);
            acc += __int_as_float(p5.y) * b2f4(r5);
            acc += __int_as_float(p6.y) * b2f4(r6);
            acc += __int_as_float(p7.y) * b2f4(r7);
        }
        for (; e + 3 < re; e += 4) {
            int2 p0 = csr_sn[e + 0], p1 = csr_sn[e + 1], p2 = csr_sn[e + 2], p3 = csr_sn[e + 3];
            ushort4 r0 = *(const ushort4*)(tb + (size_t)p0.x * 128 + c);
            ushort4 r1 = *(const ushort4*)(tb + (size_t)p1.x * 128 + c);
            ushort4 r2 = *(const ushort4*)(tb + (size_t)p2.x * 128 + c);
            ushort4 r3 = *(const ushort4*)(tb + (size_t)p3.x * 128 + c);
            acc += __int_as_float(p0.y) * b2f4(r0);
            acc += __int_as_float(p1.y) * b2f4(r1);
            acc += __int_as_float(p2.y) * b2f4(r2);
            acc += __int_as_float(p3.y) * b2f4(r3);
        }
        for (; e < re; ++e) {
            int2 p0 = csr_sn[e];
            acc += __int_as_float(p0.y) * b2f4(*(const ushort4*)(tb + (size_t)p0.x * 128 + c));
        }
        if (RELU) {
            #pragma unroll
            for (int j = 0; j < 4; ++j) acc[j] = fmaxf(acc[j], 0.f);
        }
        unsigned int u0 = (unsigned int)f2b(acc[0]) | ((unsigned int)f2b(acc[1]) << 16);
        unsigned int u1 = (unsigned int)f2b(acc[2]) | ((unsigned int)f2b(acc[3]) << 16);
        *(uint2*)&hl[p * 8 + nloc][c] = make_uint2(u0, u1);
    }

    // ---- weight fragments ----
    int wid = tid >> 6, lane = tid & 63;
    int lg = lane >> 4, l15 = lane & 15;
    bf16x8 a[MT][4];
    #pragma unroll
    for (int mt = 0; mt < MT; ++mt) {
        int jc = wid * (MT * 16) + mt * 16 + l15;
        int koff = UV ? (jc >> 7) * 128 : 0;
        int col = jc & 127;
        #pragma unroll
        for (int kk = 0; kk < 4; ++kk) {
            bf16x8 af;
            #pragma unroll
            for (int ee = 0; ee < 8; ++ee)
                af[ee] = (short)f2b(W[(size_t)(koff + kk * 32 + lg * 8 + ee) * 128 + col]);
            a[mt][kk] = af;
        }
    }
    __syncthreads();

    // ---- GEMM ----
    f32x4 acc2[MT][4];
    #pragma unroll
    for (int mt = 0; mt < MT; ++mt)
        #pragma unroll
        for (int nt = 0; nt < 4; ++nt) acc2[mt][nt] = (f32x4){0.f, 0.f, 0.f, 0.f};
    #pragma unroll
    for (int kk = 0; kk < 4; ++kk) {
        #pragma unroll
        for (int nt = 0; nt < 4; ++nt) {
            bf16x8 b = *(const bf16x8*)&hl[nt * 16 + l15][kk * 32 + lg * 8];
            #pragma unroll
            for (int mt = 0; mt < MT; ++mt)
                acc2[mt][nt] = __builtin_amdgcn_mfma_f32_16x16x32_bf16(a[mt][kk], b, acc2[mt][nt], 0, 0, 0);
        }
    }
    constexpr int OC = UV ? 256 : 128;
    #pragma unroll
    for (int mt = 0; mt < MT; ++mt) {
        int jc = wid * (MT * 16) + mt * 16 + lg * 4;
        #pragma unroll
        for (int nt = 0; nt < 4; ++nt) {
            int node = tilebase + nt * 16 + l15;
            if (node < N) {
                unsigned int u0 = (unsigned int)f2b(acc2[mt][nt][0]) | ((unsigned int)f2b(acc2[mt][nt][1]) << 16);
                unsigned int u1 = (unsigned int)f2b(acc2[mt][nt][2]) | ((unsigned int)f2b(acc2[mt][nt][3]) << 16);
                *(uint2*)(outb + (size_t)node * OC + jc) = make_uint2(u0, u1);
            }
        }
    }
}

// ---------------- edge head (CSR order, pipelined) ----------------

__global__ __launch_bounds__(256, 3) void edge_head4(
        const unsigned short* __restrict__ uvb, const int2* __restrict__ csr_sn,
        const int* __restrict__ csr_dst, const int* __restrict__ csr_eid,
        const float* __restrict__ bm1, const float* __restrict__ Wm2,
        const float* __restrict__ bm2, float* __restrict__ out, int E, int ntiles) {
    __shared__ __align__(16) unsigned short zl[64][136];
    __shared__ int eid_l[64];
    int tid = threadIdx.x;
    int wid = tid >> 6, lane = tid & 63;
    int lg = lane >> 4, l15 = lane & 15;
    int es = tid >> 4;
    int ci = tid & 15;
    int c0 = ci * 8;

    bf16x8 a2[2][4];
    float b2v[2][4];
    #pragma unroll
    for (int mt = 0; mt < 2; ++mt) {
        int m = wid * 32 + mt * 16 + l15;
        #pragma unroll
        for (int kk = 0; kk < 4; ++kk) {
            bf16x8 af;
            #pragma unroll
            for (int ee = 0; ee < 8; ++ee)
                af[ee] = (short)f2b(Wm2[(size_t)(kk * 32 + lg * 8 + ee) * 128 + m]);
            a2[mt][kk] = af;
        }
        #pragma unroll
        for (int r = 0; r < 4; ++r)
            b2v[mt][r] = bm2[wid * 32 + mt * 16 + lg * 4 + r];
    }
    float bm1v[8];
    #pragma unroll
    for (int j = 0; j < 8; ++j) bm1v[j] = bm1[c0 + j];

    uint4 uuA[4], uuB[4];
    int dA[4], dB[4], eidA[4], eidB[4];

    auto stage = [&](int tile, uint4 (&uu)[4], int (&dd)[4], int (&ee)[4]) {
        #pragma unroll
        for (int p = 0; p < 4; ++p) {
            int slot = tile * 64 + p * 16 + es;
            int cs = (slot < E) ? slot : (E - 1);
            int s = csr_sn[cs].x;
            dd[p] = csr_dst[cs];
            ee[p] = (slot < E) ? csr_eid[cs] : -1;
            uu[p] = *(const uint4*)(uvb + (size_t)s * 256 + c0);
        }
    };

    int t = blockIdx.x;
    if (t < ntiles) stage(t, uuA, dA, eidA);
    for (; t < ntiles; t += gridDim.x) {
        __syncthreads();
        #pragma unroll
        for (int p = 0; p < 4; ++p) {
            uint4 vv = *(const uint4*)(uvb + (size_t)dA[p] * 256 + 128 + c0);
            uint4 uu = uuA[p];
            float z0 = fmaxf(b2f((unsigned short)(uu.x)) + b2f((unsigned short)(vv.x)) + bm1v[0], 0.f);
            float z1 = fmaxf(b2f((unsigned short)(uu.x >> 16)) + b2f((unsigned short)(vv.x >> 16)) + bm1v[1], 0.f);
            float z2 = fmaxf(b2f((unsigned short)(uu.y)) + b2f((unsigned short)(vv.y)) + bm1v[2], 0.f);
            float z3 = fmaxf(b2f((unsigned short)(uu.y >> 16)) + b2f((unsigned short)(vv.y >> 16)) + bm1v[3], 0.f);
            float z4 = fmaxf(b2f((unsigned short)(uu.z)) + b2f((unsigned short)(vv.z)) + bm1v[4], 0.f);
            float z5 = fmaxf(b2f((unsigned short)(uu.z >> 16)) + b2f((unsigned short)(vv.z >> 16)) + bm1v[5], 0.f);
            float z6 = fmaxf(b2f((unsigned short)(uu.w)) + b2f((unsigned short)(vv.w)) + bm1v[6], 0.f);
            float z7 = fmaxf(b2f((unsigned short)(uu.w >> 16)) + b2f((unsigned short)(vv.w >> 16)) + bm1v[7], 0.f);
            uint4 w;
            w.x = (unsigned int)f2b(z0) | ((unsigned int)f2b(z1) << 16);
            w.y = (unsigned int)f2b(z2) | ((unsigned int)f2b(z3) << 16);
            w.z = (unsigned int)f2b(z4) | ((unsigned int)f2b(z5) << 16);
            w.w = (unsigned int)f2b(z6) | ((unsigned int)f2b(z7) << 16);
            *(uint4*)&zl[p * 16 + es][c0] = w;
            if (ci == 0) eid_l[p * 16 + es] = eidA[p];
        }
        int tn = t + gridDim.x;
        bool more = (tn < ntiles);
        if (more) stage(tn, uuB, dB, eidB);
        __syncthreads();

        f32x4 c2[2][4];
        #pragma unroll
        for (int mt = 0; mt < 2; ++mt)
            #pragma unroll
            for (int nt = 0; nt < 4; ++nt) c2[mt][nt] = (f32x4){0.f, 0.f, 0.f, 0.f};
        #pragma unroll
        for (int kk = 0; kk < 4; ++kk) {
            #pragma unroll
            for (int nt = 0; nt < 4; ++nt) {
                bf16x8 b = *(const bf16x8*)&zl[nt * 16 + l15][kk * 32 + lg * 8];
                c2[0][nt] = __builtin_amdgcn_mfma_f32_16x16x32_bf16(a2[0][kk], b, c2[0][nt], 0, 0, 0);
                c2[1][nt] = __builtin_amdgcn_mfma_f32_16x16x32_bf16(a2[1][kk], b, c2[1][nt], 0, 0, 0);
            }
        }
        #pragma unroll
        for (int mt = 0; mt < 2; ++mt) {
            #pragma unroll
            for (int nt = 0; nt < 4; ++nt) {
                int eg = eid_l[nt * 16 + l15];
                if (eg >= 0) {
                    f32x4 o;
                    #pragma unroll
                    for (int r = 0; r < 4; ++r) o[r] = c2[mt][nt][r] + b2v[mt][r];
                    *(f32x4*)(out + (size_t)eg * 128 + wid * 32 + mt * 16 + lg * 4) = o;
                }
            }
        }
        if (more) {
            #pragma unroll
            for (int p = 0; p < 4; ++p) {
                uuA[p] = uuB[p]; dA[p] = dB[p]; eidA[p] = eidB[p];
            }
        }
    }
}

// ---------------- launch ----------------

extern "C" void kernel_launch(void* const* d_in, const int* in_sizes, int n_in,
                              void* d_out, int out_size, void* d_ws, size_t ws_size,
                              hipStream_t stream) {
    const float* x  = (const float*)d_in[0];
    const int*   ei = (const int*)d_in[1];
    const float* W1 = (const float*)d_in[2];
    const float* b1 = (const float*)d_in[3];
    const float* W2 = (const float*)d_in[4];
    const float* b2 = (const float*)d_in[5];
    const float* W3 = (const float*)d_in[6];
    const float* b3 = (const float*)d_in[7];
    const float* Wm1 = (const float*)d_in[8];
    const float* bm1 = (const float*)d_in[9];
    const float* Wm2 = (const float*)d_in[10];
    const float* bm2 = (const float*)d_in[11];
    float* out = (float*)d_out;

    const int N = in_sizes[0] / 128;
    const int E = in_sizes[1] / 2;
    const int* src = ei;
    const int* dstp = ei + E;

    uintptr_t base = (uintptr_t)d_ws;
    auto alloc = [&](size_t bytes) -> void* {
        uintptr_t p = base;
        base += (bytes + 255) & ~(uintptr_t)255;
        return (void*)p;
    };
    int*   counts   = (int*)alloc((size_t)(N + 1) * 4);
    int*   rowstart = (int*)alloc((size_t)(N + 1) * 4);
    int*   cursor   = (int*)alloc((size_t)N * 4);
    float* dinv     = (float*)alloc((size_t)N * 4);
    int*   psum     = (int*)alloc(4096);
    int2*  csr_sn   = (int2*)alloc((size_t)E * 8);
    int*   csr_d    = (int*)alloc((size_t)E * 4);
    int*   csr_e    = (int*)alloc((size_t)E * 4);
    int2*  csr_sn2  = (int2*)alloc((size_t)E * 8);
    int*   csr_e2   = (int*)alloc((size_t)E * 4);
    unsigned short* tb1 = (unsigned short*)alloc((size_t)N * 128 * 2);
    unsigned short* tb2 = (unsigned short*)alloc((size_t)N * 128 * 2);
    unsigned short* uvb = (unsigned short*)alloc((size_t)N * 256 * 2);
    (void)ws_size; (void)n_in; (void)out_size;

    hipMemsetAsync(counts, 0, (size_t)(N + 1) * 4, stream);

    int egrid = (E + 255) / 256;
    int nchunk = (N + 1023) / 1024;
    int ggrid = (N + 63) / 64;

    // count_deg (blocks [0,egrid)) fused with gemm1 (blocks [egrid, egrid+ggrid))
    count_and_gemm1<<<egrid + ggrid, 256, 0, stream>>>(dstp, E, counts, egrid, x, W1, tb1, N);
    scan_s1<<<nchunk, 1024, 0, stream>>>(counts, N, rowstart, dinv, psum);
    scan_s23<<<nchunk, 1024, 0, stream>>>(psum, nchunk, rowstart, N, cursor);
    fill_csr<<<egrid, 256, 0, stream>>>(src, dstp, E, cursor, dinv, csr_sn, csr_d, csr_e);
    // deterministic within-bucket order (sorted by eid) -> replay-stable fp32 sums
    rank_csr<<<egrid, 256, 0, stream>>>(rowstart, csr_d, csr_sn, csr_e, csr_sn2, csr_e2, E);

    // layer boundaries: aggregate fused with following GEMM (h never materialized)
    agg_gemm<1, 0><<<ggrid, 256, 0, stream>>>(tb1, rowstart, csr_sn2, dinv, b1, W2, tb2, N);
    agg_gemm<1, 0><<<ggrid, 256, 0, stream>>>(tb2, rowstart, csr_sn2, dinv, b2, W3, tb1, N);
    agg_gemm<0, 1><<<ggrid, 256, 0, stream>>>(tb1, rowstart, csr_sn2, dinv, b3, Wm1, uvb, N);

    int ntiles = (E + 63) / 64;
    int hgrid = ntiles < 768 ? ntiles : 768;
    edge_head4<<<hgrid, 256, 0, stream>>>(uvb, csr_sn2, csr_d, csr_e2, bm1, Wm2, bm2, out, E, ntiles);
}

// Round 10
// 433.970 us; speedup vs baseline: 1.1493x; 1.1493x over previous
//
#include <hip/hip_runtime.h>
#include <stdint.h>

typedef __attribute__((ext_vector_type(8))) short bf16x8;
typedef __attribute__((ext_vector_type(4))) float f32x4;

static __device__ __forceinline__ unsigned short f2b(float f) {
    unsigned int u = __float_as_uint(f);
    unsigned int r = u + 0x7fffu + ((u >> 16) & 1u);   // RNE
    return (unsigned short)(r >> 16);
}
static __device__ __forceinline__ float b2f(unsigned short u) {
    return __uint_as_float((unsigned int)u << 16);
}
static __device__ __forceinline__ f32x4 b2f4(ushort4 u) {
    f32x4 r;
    r[0] = b2f(u.x); r[1] = b2f(u.y); r[2] = b2f(u.z); r[3] = b2f(u.w);
    return r;
}

// ---------------- fused: count_deg (blocks [0,ecnt)) + gemm1 fp32->bf16 (rest) ----------------

__global__ __launch_bounds__(256) void count_and_gemm1(
        const int* __restrict__ dst, int E, int* __restrict__ counts, int ecnt,
        const float* __restrict__ x, const float* __restrict__ W1,
        unsigned short* __restrict__ outb, int N) {
    __shared__ __align__(16) unsigned short hl[64][136];
    int tid = threadIdx.x;
    if ((int)blockIdx.x < ecnt) {
        int e = blockIdx.x * 256 + tid;
        if (e < E) atomicAdd(&counts[dst[e]], 1);
        return;
    }
    int tilebase = (blockIdx.x - ecnt) * 64;
    int wid = tid >> 6, lane = tid & 63;
    int lg = lane >> 4, l15 = lane & 15;

    bf16x8 a[2][4];
    #pragma unroll
    for (int mt = 0; mt < 2; ++mt) {
        int col = wid * 32 + mt * 16 + l15;
        #pragma unroll
        for (int kk = 0; kk < 4; ++kk) {
            bf16x8 af;
            #pragma unroll
            for (int ee = 0; ee < 8; ++ee)
                af[ee] = (short)f2b(W1[(size_t)(kk * 32 + lg * 8 + ee) * 128 + col]);
            a[mt][kk] = af;
        }
    }
    #pragma unroll
    for (int p = 0; p < 4; ++p) {
        int idx = p * 256 + tid;
        int r = idx >> 4, ci = idx & 15;
        int row = tilebase + r;
        if (row >= N) row = N - 1;
        const float* ip = x + (size_t)row * 128 + ci * 8;
        f32x4 x0 = *(const f32x4*)ip;
        f32x4 x1 = *(const f32x4*)(ip + 4);
        uint4 v;
        v.x = (unsigned int)f2b(x0[0]) | ((unsigned int)f2b(x0[1]) << 16);
        v.y = (unsigned int)f2b(x0[2]) | ((unsigned int)f2b(x0[3]) << 16);
        v.z = (unsigned int)f2b(x1[0]) | ((unsigned int)f2b(x1[1]) << 16);
        v.w = (unsigned int)f2b(x1[2]) | ((unsigned int)f2b(x1[3]) << 16);
        *(uint4*)&hl[r][ci * 8] = v;
    }
    __syncthreads();

    f32x4 acc[2][4];
    #pragma unroll
    for (int mt = 0; mt < 2; ++mt)
        #pragma unroll
        for (int nt = 0; nt < 4; ++nt) acc[mt][nt] = (f32x4){0.f, 0.f, 0.f, 0.f};
    #pragma unroll
    for (int kk = 0; kk < 4; ++kk) {
        #pragma unroll
        for (int nt = 0; nt < 4; ++nt) {
            bf16x8 b = *(const bf16x8*)&hl[nt * 16 + l15][kk * 32 + lg * 8];
            acc[0][nt] = __builtin_amdgcn_mfma_f32_16x16x32_bf16(a[0][kk], b, acc[0][nt], 0, 0, 0);
            acc[1][nt] = __builtin_amdgcn_mfma_f32_16x16x32_bf16(a[1][kk], b, acc[1][nt], 0, 0, 0);
        }
    }
    #pragma unroll
    for (int mt = 0; mt < 2; ++mt) {
        int j = wid * 32 + mt * 16 + lg * 4;
        #pragma unroll
        for (int nt = 0; nt < 4; ++nt) {
            int node = tilebase + nt * 16 + l15;
            if (node < N) {
                unsigned int u0 = (unsigned int)f2b(acc[mt][nt][0]) | ((unsigned int)f2b(acc[mt][nt][1]) << 16);
                unsigned int u1 = (unsigned int)f2b(acc[mt][nt][2]) | ((unsigned int)f2b(acc[mt][nt][3]) << 16);
                *(uint2*)(outb + (size_t)node * 128 + j) = make_uint2(u0, u1);
            }
        }
    }
}

// ---------------- CSR build ----------------

__global__ void scan_s1(const int* __restrict__ counts, int N,
                        int* __restrict__ rowstart, float* __restrict__ dinv,
                        int* __restrict__ psum) {
    __shared__ int wsum[16];
    int tid = threadIdx.x, wave = tid >> 6, lane = tid & 63;
    int i = blockIdx.x * 1024 + tid;
    int c = (i < N) ? counts[i] : 0;
    int x = c;
    #pragma unroll
    for (int off = 1; off < 64; off <<= 1) {
        int v = __shfl_up(x, off);
        if (lane >= off) x += v;
    }
    if (lane == 63) wsum[wave] = x;
    __syncthreads();
    int pre = 0, tot = 0;
    #pragma unroll
    for (int w = 0; w < 16; ++w) {
        int s = wsum[w];
        tot += s;
        if (w < wave) pre += s;
    }
    if (i < N) {
        rowstart[i] = pre + x - c;
        dinv[i] = rsqrtf((float)c + 1.0f);
    }
    if (tid == 0) psum[blockIdx.x] = tot;
}

// merged s2+s3: each block locally re-scans psum (nchunk <= 64)
__global__ void scan_s23(const int* __restrict__ psum, int nchunk,
                         int* __restrict__ rowstart, int N, int* __restrict__ cursor) {
    int b = blockIdx.x;
    int pre = 0, tot = 0;
    for (int w = 0; w < nchunk; ++w) {
        int s = psum[w];
        tot += s;
        if (w < b) pre += s;
    }
    int i = b * 1024 + threadIdx.x;
    if (i < N) {
        int r = rowstart[i] + pre;
        rowstart[i] = r;
        cursor[i] = r;
    }
    if (b == 0 && threadIdx.x == 0) rowstart[N] = tot;
}

// packs (src, norm=dinv[src]*dinv[dst]) per CSR slot (arbitrary order within bucket)
__global__ void fill_csr(const int* __restrict__ src, const int* __restrict__ dst, int E,
                         int* __restrict__ cursor, const float* __restrict__ dinv,
                         int2* __restrict__ csr_sn, int* __restrict__ csr_dst,
                         int* __restrict__ csr_eid) {
    int e = blockIdx.x * 256 + threadIdx.x;
    if (e < E) {
        int d = dst[e], s = src[e];
        int p = atomicAdd(&cursor[d], 1);
        float nrm = dinv[s] * dinv[d];
        csr_sn[p] = make_int2(s, __float_as_int(nrm));
        csr_dst[p] = d;
        csr_eid[p] = e;
    }
}

// deterministic re-order: slot -> rowstart[d] + rank(eid within bucket).
// eids unique -> bijection; layout bit-identical every call -> replay-stable sums.
// also emits int4 (s, d, eid, norm) for the edge head's single-load staging.
__global__ void rank_csr(const int* __restrict__ rowstart, const int* __restrict__ csr_dst,
                         const int2* __restrict__ csr_sn, const int* __restrict__ csr_eid,
                         int2* __restrict__ csr_sn2, int4* __restrict__ csr_sde, int E) {
    int p = blockIdx.x * 256 + threadIdx.x;
    if (p >= E) return;
    int d = csr_dst[p];
    int rs = rowstart[d], re = rowstart[d + 1];
    int my = csr_eid[p];
    int rank = 0;
    for (int q = rs; q < re; ++q) rank += (csr_eid[q] < my);
    int2 sn = csr_sn[p];
    csr_sn2[rs + rank] = sn;
    csr_sde[rs + rank] = make_int4(sn.x, d, my, sn.y);
}

// ---------------- node GEMM via MFMA (bf16 in): t = h @ W ----------------

__global__ __launch_bounds__(256) void node_mfma(const unsigned short* __restrict__ inp,
                                                 const float* __restrict__ W,
                                                 unsigned short* __restrict__ outb, int N) {
    __shared__ __align__(16) unsigned short hl[64][136];
    int tid = threadIdx.x;
    int wid = tid >> 6, lane = tid & 63;
    int lg = lane >> 4, l15 = lane & 15;
    int tilebase = blockIdx.x * 64;

    bf16x8 a[2][4];
    #pragma unroll
    for (int mt = 0; mt < 2; ++mt) {
        int col = wid * 32 + mt * 16 + l15;
        #pragma unroll
        for (int kk = 0; kk < 4; ++kk) {
            bf16x8 af;
            #pragma unroll
            for (int ee = 0; ee < 8; ++ee)
                af[ee] = (short)f2b(W[(size_t)(kk * 32 + lg * 8 + ee) * 128 + col]);
            a[mt][kk] = af;
        }
    }
    #pragma unroll
    for (int p = 0; p < 4; ++p) {
        int idx = p * 256 + tid;
        int r = idx >> 4, ci = idx & 15;
        int row = tilebase + r;
        if (row >= N) row = N - 1;
        *(uint4*)&hl[r][ci * 8] = *(const uint4*)(inp + (size_t)row * 128 + ci * 8);
    }
    __syncthreads();

    f32x4 acc[2][4];
    #pragma unroll
    for (int mt = 0; mt < 2; ++mt)
        #pragma unroll
        for (int nt = 0; nt < 4; ++nt) acc[mt][nt] = (f32x4){0.f, 0.f, 0.f, 0.f};
    #pragma unroll
    for (int kk = 0; kk < 4; ++kk) {
        #pragma unroll
        for (int nt = 0; nt < 4; ++nt) {
            bf16x8 b = *(const bf16x8*)&hl[nt * 16 + l15][kk * 32 + lg * 8];
            acc[0][nt] = __builtin_amdgcn_mfma_f32_16x16x32_bf16(a[0][kk], b, acc[0][nt], 0, 0, 0);
            acc[1][nt] = __builtin_amdgcn_mfma_f32_16x16x32_bf16(a[1][kk], b, acc[1][nt], 0, 0, 0);
        }
    }
    #pragma unroll
    for (int mt = 0; mt < 2; ++mt) {
        int j = wid * 32 + mt * 16 + lg * 4;
        #pragma unroll
        for (int nt = 0; nt < 4; ++nt) {
            int node = tilebase + nt * 16 + l15;
            if (node < N) {
                unsigned int u0 = (unsigned int)f2b(acc[mt][nt][0]) | ((unsigned int)f2b(acc[mt][nt][1]) << 16);
                unsigned int u1 = (unsigned int)f2b(acc[mt][nt][2]) | ((unsigned int)f2b(acc[mt][nt][3]) << 16);
                *(uint2*)(outb + (size_t)node * 128 + j) = make_uint2(u0, u1);
            }
        }
    }
}

// ---------------- GCN aggregation: packed (src,norm), 8-row batches, 8 nodes/block ----------------

template <int RELU>
__global__ __launch_bounds__(256) void aggregate(
        const unsigned short* __restrict__ tb, const int* __restrict__ rowstart,
        const int2* __restrict__ csr_sn, const float* __restrict__ dinv,
        const float* __restrict__ bias, unsigned short* __restrict__ hb, int N) {
    int tid = threadIdx.x;
    int node = blockIdx.x * 8 + (tid >> 5);
    if (node >= N) return;
    int c = (tid & 31) * 4;
    float di = dinv[node];
    f32x4 self = b2f4(*(const ushort4*)(tb + (size_t)node * 128 + c));
    f32x4 acc = *(const f32x4*)(bias + c) + (di * di) * self;
    int e = rowstart[node], re = rowstart[node + 1];
    for (; e + 7 < re; e += 8) {
        int2 p0 = csr_sn[e + 0], p1 = csr_sn[e + 1], p2 = csr_sn[e + 2], p3 = csr_sn[e + 3];
        int2 p4 = csr_sn[e + 4], p5 = csr_sn[e + 5], p6 = csr_sn[e + 6], p7 = csr_sn[e + 7];
        ushort4 r0 = *(const ushort4*)(tb + (size_t)p0.x * 128 + c);
        ushort4 r1 = *(const ushort4*)(tb + (size_t)p1.x * 128 + c);
        ushort4 r2 = *(const ushort4*)(tb + (size_t)p2.x * 128 + c);
        ushort4 r3 = *(const ushort4*)(tb + (size_t)p3.x * 128 + c);
        ushort4 r4 = *(const ushort4*)(tb + (size_t)p4.x * 128 + c);
        ushort4 r5 = *(const ushort4*)(tb + (size_t)p5.x * 128 + c);
        ushort4 r6 = *(const ushort4*)(tb + (size_t)p6.x * 128 + c);
        ushort4 r7 = *(const ushort4*)(tb + (size_t)p7.x * 128 + c);
        acc += __int_as_float(p0.y) * b2f4(r0);
        acc += __int_as_float(p1.y) * b2f4(r1);
        acc += __int_as_float(p2.y) * b2f4(r2);
        acc += __int_as_float(p3.y) * b2f4(r3);
        acc += __int_as_float(p4.y) * b2f4(r4);
        acc += __int_as_float(p5.y) * b2f4(r5);
        acc += __int_as_float(p6.y) * b2f4(r6);
        acc += __int_as_float(p7.y) * b2f4(r7);
    }
    for (; e + 3 < re; e += 4) {
        int2 p0 = csr_sn[e + 0], p1 = csr_sn[e + 1], p2 = csr_sn[e + 2], p3 = csr_sn[e + 3];
        ushort4 r0 = *(const ushort4*)(tb + (size_t)p0.x * 128 + c);
        ushort4 r1 = *(const ushort4*)(tb + (size_t)p1.x * 128 + c);
        ushort4 r2 = *(const ushort4*)(tb + (size_t)p2.x * 128 + c);
        ushort4 r3 = *(const ushort4*)(tb + (size_t)p3.x * 128 + c);
        acc += __int_as_float(p0.y) * b2f4(r0);
        acc += __int_as_float(p1.y) * b2f4(r1);
        acc += __int_as_float(p2.y) * b2f4(r2);
        acc += __int_as_float(p3.y) * b2f4(r3);
    }
    for (; e < re; ++e) {
        int2 p0 = csr_sn[e];
        acc += __int_as_float(p0.y) * b2f4(*(const ushort4*)(tb + (size_t)p0.x * 128 + c));
    }
    if (RELU) {
        #pragma unroll
        for (int j = 0; j < 4; ++j) acc[j] = fmaxf(acc[j], 0.f);
    }
    unsigned int u0 = (unsigned int)f2b(acc[0]) | ((unsigned int)f2b(acc[1]) << 16);
    unsigned int u1 = (unsigned int)f2b(acc[2]) | ((unsigned int)f2b(acc[3]) << 16);
    *(uint2*)(hb + (size_t)node * 128 + c) = make_uint2(u0, u1);
}

// ---------------- uv precompute: bf16 out ----------------

__global__ __launch_bounds__(256) void uv_gemm(const unsigned short* __restrict__ h3b,
                                               const float* __restrict__ Wm1,
                                               unsigned short* __restrict__ uvb, int N) {
    __shared__ __align__(16) unsigned short hl[64][136];
    int tid = threadIdx.x;
    int wid = tid >> 6, lane = tid & 63;
    int lg = lane >> 4, l15 = lane & 15;
    int tilebase = blockIdx.x * 64;

    bf16x8 a[4][4];
    #pragma unroll
    for (int mt = 0; mt < 4; ++mt) {
        int jc = wid * 64 + mt * 16 + l15;
        int koff = (jc >> 7) * 128;
        int col = jc & 127;
        #pragma unroll
        for (int kk = 0; kk < 4; ++kk) {
            bf16x8 af;
            #pragma unroll
            for (int ee = 0; ee < 8; ++ee)
                af[ee] = (short)f2b(Wm1[(size_t)(koff + kk * 32 + lg * 8 + ee) * 128 + col]);
            a[mt][kk] = af;
        }
    }

    #pragma unroll
    for (int p = 0; p < 4; ++p) {
        int idx = p * 256 + tid;
        int r = idx >> 4, ci = idx & 15;
        int row = tilebase + r;
        if (row >= N) row = N - 1;
        uint4 v = *(const uint4*)(h3b + (size_t)row * 128 + ci * 8);
        *(uint4*)&hl[r][ci * 8] = v;
    }
    __syncthreads();

    f32x4 acc[4][4];
    #pragma unroll
    for (int mt = 0; mt < 4; ++mt)
        #pragma unroll
        for (int nt = 0; nt < 4; ++nt) acc[mt][nt] = (f32x4){0.f, 0.f, 0.f, 0.f};
    #pragma unroll
    for (int kk = 0; kk < 4; ++kk) {
        #pragma unroll
        for (int nt = 0; nt < 4; ++nt) {
            bf16x8 b = *(const bf16x8*)&hl[nt * 16 + l15][kk * 32 + lg * 8];
            #pragma unroll
            for (int mt = 0; mt < 4; ++mt)
                acc[mt][nt] = __builtin_amdgcn_mfma_f32_16x16x32_bf16(a[mt][kk], b, acc[mt][nt], 0, 0, 0);
        }
    }
    #pragma unroll
    for (int mt = 0; mt < 4; ++mt) {
        int jc = wid * 64 + mt * 16 + lg * 4;
        #pragma unroll
        for (int nt = 0; nt < 4; ++nt) {
            int node = tilebase + nt * 16 + l15;
            if (node < N) {
                unsigned int u0 = (unsigned int)f2b(acc[mt][nt][0]) | ((unsigned int)f2b(acc[mt][nt][1]) << 16);
                unsigned int u1 = (unsigned int)f2b(acc[mt][nt][2]) | ((unsigned int)f2b(acc[mt][nt][3]) << 16);
                *(uint2*)(uvb + (size_t)node * 256 + jc) = make_uint2(u0, u1);
            }
        }
    }
}

// ---------------- edge head (CSR order, pipelined) ----------------

__global__ __launch_bounds__(256, 3) void edge_head4(
        const unsigned short* __restrict__ uvb, const int4* __restrict__ csr_sde,
        const float* __restrict__ bm1, const float* __restrict__ Wm2,
        const float* __restrict__ bm2, float* __restrict__ out, int E, int ntiles) {
    __shared__ __align__(16) unsigned short zl[64][136];
    __shared__ int eid_l[64];
    int tid = threadIdx.x;
    int wid = tid >> 6, lane = tid & 63;
    int lg = lane >> 4, l15 = lane & 15;
    int es = tid >> 4;
    int ci = tid & 15;
    int c0 = ci * 8;

    bf16x8 a2[2][4];
    float b2v[2][4];
    #pragma unroll
    for (int mt = 0; mt < 2; ++mt) {
        int m = wid * 32 + mt * 16 + l15;
        #pragma unroll
        for (int kk = 0; kk < 4; ++kk) {
            bf16x8 af;
            #pragma unroll
            for (int ee = 0; ee < 8; ++ee)
                af[ee] = (short)f2b(Wm2[(size_t)(kk * 32 + lg * 8 + ee) * 128 + m]);
            a2[mt][kk] = af;
        }
        #pragma unroll
        for (int r = 0; r < 4; ++r)
            b2v[mt][r] = bm2[wid * 32 + mt * 16 + lg * 4 + r];
    }
    float bm1v[8];
    #pragma unroll
    for (int j = 0; j < 8; ++j) bm1v[j] = bm1[c0 + j];

    uint4 uuA[4], uuB[4];
    int dA[4], dB[4], eidA[4], eidB[4];

    auto stage = [&](int tile, uint4 (&uu)[4], int (&dd)[4], int (&ee)[4]) {
        #pragma unroll
        for (int p = 0; p < 4; ++p) {
            int slot = tile * 64 + p * 16 + es;
            int cs = (slot < E) ? slot : (E - 1);
            int4 sde = csr_sde[cs];
            dd[p] = sde.y;
            ee[p] = (slot < E) ? sde.z : -1;
            uu[p] = *(const uint4*)(uvb + (size_t)sde.x * 256 + c0);
        }
    };

    int t = blockIdx.x;
    if (t < ntiles) stage(t, uuA, dA, eidA);
    for (; t < ntiles; t += gridDim.x) {
        __syncthreads();
        #pragma unroll
        for (int p = 0; p < 4; ++p) {
            uint4 vv = *(const uint4*)(uvb + (size_t)dA[p] * 256 + 128 + c0);
            uint4 uu = uuA[p];
            float z0 = fmaxf(b2f((unsigned short)(uu.x)) + b2f((unsigned short)(vv.x)) + bm1v[0], 0.f);
            float z1 = fmaxf(b2f((unsigned short)(uu.x >> 16)) + b2f((unsigned short)(vv.x >> 16)) + bm1v[1], 0.f);
            float z2 = fmaxf(b2f((unsigned short)(uu.y)) + b2f((unsigned short)(vv.y)) + bm1v[2], 0.f);
            float z3 = fmaxf(b2f((unsigned short)(uu.y >> 16)) + b2f((unsigned short)(vv.y >> 16)) + bm1v[3], 0.f);
            float z4 = fmaxf(b2f((unsigned short)(uu.z)) + b2f((unsigned short)(vv.z)) + bm1v[4], 0.f);
            float z5 = fmaxf(b2f((unsigned short)(uu.z >> 16)) + b2f((unsigned short)(vv.z >> 16)) + bm1v[5], 0.f);
            float z6 = fmaxf(b2f((unsigned short)(uu.w)) + b2f((unsigned short)(vv.w)) + bm1v[6], 0.f);
            float z7 = fmaxf(b2f((unsigned short)(uu.w >> 16)) + b2f((unsigned short)(vv.w >> 16)) + bm1v[7], 0.f);
            uint4 w;
            w.x = (unsigned int)f2b(z0) | ((unsigned int)f2b(z1) << 16);
            w.y = (unsigned int)f2b(z2) | ((unsigned int)f2b(z3) << 16);
            w.z = (unsigned int)f2b(z4) | ((unsigned int)f2b(z5) << 16);
            w.w = (unsigned int)f2b(z6) | ((unsigned int)f2b(z7) << 16);
            *(uint4*)&zl[p * 16 + es][c0] = w;
            if (ci == 0) eid_l[p * 16 + es] = eidA[p];
        }
        int tn = t + gridDim.x;
        bool more = (tn < ntiles);
        if (more) stage(tn, uuB, dB, eidB);
        __syncthreads();

        f32x4 c2[2][4];
        #pragma unroll
        for (int mt = 0; mt < 2; ++mt)
            #pragma unroll
            for (int nt = 0; nt < 4; ++nt) c2[mt][nt] = (f32x4){0.f, 0.f, 0.f, 0.f};
        #pragma unroll
        for (int kk = 0; kk < 4; ++kk) {
            #pragma unroll
            for (int nt = 0; nt < 4; ++nt) {
                bf16x8 b = *(const bf16x8*)&zl[nt * 16 + l15][kk * 32 + lg * 8];
                c2[0][nt] = __builtin_amdgcn_mfma_f32_16x16x32_bf16(a2[0][kk], b, c2[0][nt], 0, 0, 0);
                c2[1][nt] = __builtin_amdgcn_mfma_f32_16x16x32_bf16(a2[1][kk], b, c2[1][nt], 0, 0, 0);
            }
        }
        #pragma unroll
        for (int mt = 0; mt < 2; ++mt) {
            #pragma unroll
            for (int nt = 0; nt < 4; ++nt) {
                int eg = eid_l[nt * 16 + l15];
                if (eg >= 0) {
                    f32x4 o;
                    #pragma unroll
                    for (int r = 0; r < 4; ++r) o[r] = c2[mt][nt][r] + b2v[mt][r];
                    *(f32x4*)(out + (size_t)eg * 128 + wid * 32 + mt * 16 + lg * 4) = o;
                }
            }
        }
        if (more) {
            #pragma unroll
            for (int p = 0; p < 4; ++p) {
                uuA[p] = uuB[p]; dA[p] = dB[p]; eidA[p] = eidB[p];
            }
        }
    }
}

// ---------------- launch ----------------

extern "C" void kernel_launch(void* const* d_in, const int* in_sizes, int n_in,
                              void* d_out, int out_size, void* d_ws, size_t ws_size,
                              hipStream_t stream) {
    const float* x  = (const float*)d_in[0];
    const int*   ei = (const int*)d_in[1];
    const float* W1 = (const float*)d_in[2];
    const float* b1 = (const float*)d_in[3];
    const float* W2 = (const float*)d_in[4];
    const float* b2 = (const float*)d_in[5];
    const float* W3 = (const float*)d_in[6];
    const float* b3 = (const float*)d_in[7];
    const float* Wm1 = (const float*)d_in[8];
    const float* bm1 = (const float*)d_in[9];
    const float* Wm2 = (const float*)d_in[10];
    const float* bm2 = (const float*)d_in[11];
    float* out = (float*)d_out;

    const int N = in_sizes[0] / 128;
    const int E = in_sizes[1] / 2;
    const int* src = ei;
    const int* dstp = ei + E;

    uintptr_t base = (uintptr_t)d_ws;
    auto alloc = [&](size_t bytes) -> void* {
        uintptr_t p = base;
        base += (bytes + 255) & ~(uintptr_t)255;
        return (void*)p;
    };
    int*   counts   = (int*)alloc((size_t)(N + 1) * 4);
    int*   rowstart = (int*)alloc((size_t)(N + 1) * 4);
    int*   cursor   = (int*)alloc((size_t)N * 4);
    float* dinv     = (float*)alloc((size_t)N * 4);
    int*   psum     = (int*)alloc(4096);
    int2*  csr_sn   = (int2*)alloc((size_t)E * 8);
    int*   csr_d    = (int*)alloc((size_t)E * 4);
    int*   csr_e    = (int*)alloc((size_t)E * 4);
    int2*  csr_sn2  = (int2*)alloc((size_t)E * 8);
    int4*  csr_sde  = (int4*)alloc((size_t)E * 16);
    unsigned short* tb  = (unsigned short*)alloc((size_t)N * 128 * 2);
    unsigned short* hb  = (unsigned short*)alloc((size_t)N * 128 * 2);
    unsigned short* uvb = (unsigned short*)alloc((size_t)N * 256 * 2);
    (void)ws_size; (void)n_in; (void)out_size;

    hipMemsetAsync(counts, 0, (size_t)(N + 1) * 4, stream);

    int egrid = (E + 255) / 256;
    int nchunk = (N + 1023) / 1024;
    int ggrid = (N + 63) / 64;
    int agrid = (N + 7) / 8;

    count_and_gemm1<<<egrid + ggrid, 256, 0, stream>>>(dstp, E, counts, egrid, x, W1, tb, N);
    scan_s1<<<nchunk, 1024, 0, stream>>>(counts, N, rowstart, dinv, psum);
    scan_s23<<<nchunk, 1024, 0, stream>>>(psum, nchunk, rowstart, N, cursor);
    fill_csr<<<egrid, 256, 0, stream>>>(src, dstp, E, cursor, dinv, csr_sn, csr_d, csr_e);
    rank_csr<<<egrid, 256, 0, stream>>>(rowstart, csr_d, csr_sn, csr_e, csr_sn2, csr_sde, E);

    aggregate<1><<<agrid, 256, 0, stream>>>(tb, rowstart, csr_sn2, dinv, b1, hb, N);
    node_mfma<<<ggrid, 256, 0, stream>>>(hb, W2, tb, N);
    aggregate<1><<<agrid, 256, 0, stream>>>(tb, rowstart, csr_sn2, dinv, b2, hb, N);
    node_mfma<<<ggrid, 256, 0, stream>>>(hb, W3, tb, N);
    aggregate<0><<<agrid, 256, 0, stream>>>(tb, rowstart, csr_sn2, dinv, b3, hb, N);

    uv_gemm<<<ggrid, 256, 0, stream>>>(hb, Wm1, uvb, N);

    int ntiles = (E + 63) / 64;
    int hgrid = ntiles < 768 ? ntiles : 768;
    edge_head4<<<hgrid, 256, 0, stream>>>(uvb, csr_sde, bm1, Wm2, bm2, out, E, ntiles);
}